// Round 11
// baseline (330.521 us; speedup 1.0000x reference)
//
#include <hip/hip_runtime.h>
#include <hip/hip_fp8.h>
#include <math.h>

#define N_NODES 100000
#define N_EDGES 1600000
#define F_IN    4
#define HID     128
#define N_CLS   5
#define N_GRAPH 256
#define POOL_SEG 8

#define BSHIFT   9
#define BSIZE    512
#define NBUK     196            // 512-node scatter buckets: ceil(100000/512)
#define NQB      784            // 128-node pad/fill quarter-buckets: NBUK*4
#define NCHUNK   800
#define CHUNK    2000           // 800 * 2000 = 1.6M exactly
#define BUKCAP   9216           // per-bucket region capacity; mean 8163, sd ~90 -> +11 sigma

typedef _Float16 f16;
typedef _Float16 f16x2 __attribute__((ext_vector_type(2)));
typedef _Float16 f16x8 __attribute__((ext_vector_type(8)));
typedef float f32x4 __attribute__((ext_vector_type(4)));

// decode 4-byte edge record: [src:17 | coef-f16-positive:15]; record 0 == dummy (src 0, coef 0)
__device__ __forceinline__ float rec_coef(unsigned r) {
    return (float)__builtin_bit_cast(_Float16, (unsigned short)(r & 0x7FFFu));
}

// coef broadcast into both halves of a f16x2
__device__ __forceinline__ f16x2 rec_coef2(unsigned r) {
    unsigned c = r & 0x7FFFu;
    return __builtin_bit_cast(f16x2, (c << 16) | c);
}

__device__ __forceinline__ float2 fp8x2_to_f32x2(unsigned short raw) {
    __hip_fp8x2_e4m3 t;
    t.__x = raw;
    return static_cast<float2>(t);
}

// 2 fp8 bytes -> f16x2. gfx950 has V_CVT_PK_F16_FP8 (1 VALU); fallback via f32.
#if __has_builtin(__builtin_amdgcn_cvt_pk_f16_fp8)
__device__ __forceinline__ f16x2 cvt_h2(unsigned v) {
    auto t = __builtin_amdgcn_cvt_pk_f16_fp8((short)v);
    return __builtin_bit_cast(f16x2, t);
}
#else
__device__ __forceinline__ f16x2 cvt_h2(unsigned v) {
    float2 f = fp8x2_to_f32x2((unsigned short)v);
    auto t = __builtin_amdgcn_cvt_pkrtz(f.x, f.y);
    return __builtin_bit_cast(f16x2, t);
}
#endif

// 8 fp8 values (uint2) -> packed-f16 fma into acc[0..3] with coef pair c2 (v_pk_fma_f16)
__device__ __forceinline__ void fma8h(f16x2 c2, uint2 v, f16x2* acc) {
    acc[0] += c2 * cvt_h2(v.x);
    acc[1] += c2 * cvt_h2(v.x >> 16);
    acc[2] += c2 * cvt_h2(v.y);
    acc[3] += c2 * cvt_h2(v.y >> 16);
}

__device__ __forceinline__ f16x2 shfl_xor_h2(f16x2 a, int m) {
    return __builtin_bit_cast(f16x2, __shfl_xor(__builtin_bit_cast(int, a), m, 64));
}

// ================= CSR BUILD =================================================================
// Lessons: (r7) scattered 4B global writes cost a 64B line each -> scatters stay bucket-local
// and cursor-sequential; (r8) per-edge random global atomics are line-amplified and
// latency-bound -> degree via LDS histograms only; (r10) bucket bases via atomic range
// reservation; (r11) the build kernels were OCCUPANCY-bound (196-200 blocks = ~10% machine)
// -> 800 scatter blocks + 784 quarter-bucket hist/fill blocks; gcur strided 64B/counter.

// fused count+scatter: per chunk-block, (1) LDS histogram, (2) reserve [base,base+cnt) per
// bucket via strided global cursor, (3) re-scan chunk (L2-hot) and scatter via LDS cursors.
// record: (src:17)<<9 | (dst & 511). Within-bucket order is arbitrary (consumers don't care).
__global__ __launch_bounds__(256) void k_scatterA(const int* __restrict__ src, const int* __restrict__ dst,
                                                  int* __restrict__ gcur, unsigned* __restrict__ bkt) {
    __shared__ int cnt[NBUK];
    __shared__ int cur[NBUK];
    int t = threadIdx.x;
    if (t < NBUK) cnt[t] = 0;
    __syncthreads();
    int base = blockIdx.x * CHUNK;
#pragma unroll
    for (int it = 0; it < 8; ++it) {
        int idx = it * 256 + t;
        if (idx < CHUNK) atomicAdd(&cnt[dst[base + idx] >> BSHIFT], 1);
    }
    __syncthreads();
    if (t < NBUK) cur[t] = cnt[t] ? atomicAdd(&gcur[t * 16], cnt[t]) : 0;  // reserve range
    __syncthreads();
#pragma unroll
    for (int it = 0; it < 8; ++it) {
        int idx = it * 256 + t;
        if (idx < CHUNK) {
            int s = src[base + idx], d = dst[base + idx];
            int b = d >> BSHIFT;
            int p = atomicAdd(&cur[b], 1);
            bkt[p] = ((unsigned)s << BSHIFT) | (unsigned)(d & (BSIZE - 1));
        }
    }
}

// quarter-bucket degree hist: block qb owns nodes [qb*128, qb*128+128); scans its parent
// bucket's record range, filters to its quarter -> deg, dinv, pad-8 quarter total.
__global__ __launch_bounds__(256) void k_hist2(const unsigned* __restrict__ bkt,
                                               const int* __restrict__ gcur,
                                               int* __restrict__ deg, float* __restrict__ dinv,
                                               int* __restrict__ padTot) {
    __shared__ int hist[128];
    __shared__ int tot;
    int t = threadIdx.x, qb = blockIdx.x;
    int b = qb >> 2, q = qb & 3;
    if (t < 128) hist[t] = 0;
    if (t == 0) tot = 0;
    __syncthreads();
    int s0 = b * BUKCAP, s1 = gcur[b * 16];
    for (int e = s0 + t; e < s1; e += 256) {
        int dl = (int)(bkt[e] & (BSIZE - 1));
        if ((dl >> 7) == q) atomicAdd(&hist[dl & 127], 1);
    }
    __syncthreads();
    if (t < 128) {
        int node = qb * 128 + t;
        int d = hist[t];
        if (node < N_NODES) {
            deg[node] = d;
            dinv[node] = rsqrtf((float)d + 1.0f);
        }
        atomicAdd(&tot, (d + 7) >> 3);
    }
    __syncthreads();
    if (t == 0) padTot[qb] = tot << 3;
}

// scan NQB=784 quarter-bucket padded totals -> padded bases (single 1024-thread block).
__global__ __launch_bounds__(1024) void k_pscan(const int* __restrict__ padTot, int* __restrict__ padBase,
                                                int* __restrict__ rowptrP) {
    __shared__ int s[1024];
    int t = threadIdx.x;
    int v = (t < NQB) ? padTot[t] : 0;
    s[t] = v;
    __syncthreads();
    for (int off = 1; off < 1024; off <<= 1) {
        int u = (t >= off) ? s[t - off] : 0;
        __syncthreads();
        s[t] += u;
        __syncthreads();
    }
    if (t < NQB) padBase[t] = s[t] - v;
    if (t == 0) {
        padBase[NQB] = s[NQB - 1];
        rowptrP[N_NODES] = s[NQB - 1];
    }
}

// quarter-bucket padded CSR fill (pad-8) + coef fused; edges pre-zeroed (dummy = record 0).
// Records stored 2x4-TRANSPOSED within each 8-slot window: logical slot 2i+g at physical
// 4g+i; one dwordx4 at (win + g*4) gives group g its 4 records directly.
__global__ __launch_bounds__(256) void k_local2(const unsigned* __restrict__ bkt,
                                                const int* __restrict__ gcur,
                                                const int* __restrict__ deg,
                                                const float* __restrict__ dinv,
                                                const int* __restrict__ padBase,
                                                int* __restrict__ rowptrP,
                                                unsigned* __restrict__ edges) {
    __shared__ int sc[128];
    __shared__ int cur[128];
    __shared__ int st[128];
    __shared__ float dv[128];
    int t = threadIdx.x, qb = blockIdx.x;
    int b = qb >> 2, q = qb & 3;
    int base = padBase[qb];
    int node = qb * 128 + t;
    int pd = 0;
    if (t < 128) {
        int d = (node < N_NODES) ? deg[node] : 0;
        pd = ((d + 7) >> 3) << 3;
        sc[t] = pd;
        dv[t] = (node < N_NODES) ? dinv[node] : 0.f;
    }
    __syncthreads();
    for (int off = 1; off < 128; off <<= 1) {
        int v = 0;
        if (t < 128 && t >= off) v = sc[t - off];
        __syncthreads();
        if (t < 128) sc[t] += v;
        __syncthreads();
    }
    if (t < 128) {
        int o = base + sc[t] - pd;
        if (node < N_NODES) rowptrP[node] = o;
        cur[t] = o;
        st[t] = o;
    }
    __syncthreads();
    int s0 = b * BUKCAP, s1 = gcur[b * 16];
    for (int e = s0 + t; e < s1; e += 256) {
        unsigned r = bkt[e];
        int dl = (int)(r & (BSIZE - 1));
        if ((dl >> 7) != q) continue;
        int l = dl & 127;
        int s = (int)(r >> BSHIFT);
        int p = atomicAdd(&cur[l], 1);
        int rs = st[l];
        int sl = p - rs;                                   // logical slot in row
        int phys = rs + (sl & ~7) + (((sl & 1) << 2) | ((sl >> 1) & 3)); // 2x4 transpose in window-8
        float c = dv[l] * dinv[s];
        unsigned short cb = __builtin_bit_cast(unsigned short, (f16)c);
        edges[phys] = ((unsigned)s << 15) | (unsigned)(cb & 0x7FFFu);
    }
}

// ---------------- FUSED layer 1: wave-parallel Agg(x) + (Nx4)@(4x128) GEMM, fp8 out ---------
// Block = 256 thr = 16 node-groups of 16 lanes. Length-guarded loop -> pad-8 safe; the
// window transpose only permutes the order of an order-insensitive lane-sum.
__global__ __launch_bounds__(256) void k_aggx1(const float4* __restrict__ x,
                                               const int* __restrict__ rowptrP,
                                               const unsigned* __restrict__ edges,
                                               const float* __restrict__ dinv,
                                               const float* __restrict__ W1, const float* __restrict__ b1,
                                               unsigned* __restrict__ hA) {
    __shared__ float4 sxa[16];
    __shared__ float sW[4 * HID];
    __shared__ float sb[HID];
    int t = threadIdx.x;
    sW[t] = W1[t];
    sW[t + 256] = W1[t + 256];
    if (t < HID) sb[t] = b1[t];
    int grp = t >> 4;             // 0..15 local node
    int l = t & 15;
    int node = blockIdx.x * 16 + grp;   // grid 6250 -> exact
    int beg = rowptrP[node], end = rowptrP[node + 1];
    float ax = 0.f, ay = 0.f, az = 0.f, aw = 0.f;
    for (int e = beg + l; e < end; e += 16) {
        unsigned r = edges[e];
        float c = rec_coef(r);
        float4 v = x[r >> 15];
        ax = fmaf(c, v.x, ax); ay = fmaf(c, v.y, ay);
        az = fmaf(c, v.z, az); aw = fmaf(c, v.w, aw);
    }
#pragma unroll
    for (int off = 1; off < 16; off <<= 1) {
        ax += __shfl_xor(ax, off, 64);
        ay += __shfl_xor(ay, off, 64);
        az += __shfl_xor(az, off, 64);
        aw += __shfl_xor(aw, off, 64);
    }
    if (l == 0) {
        float di = dinv[node];
        float c0 = di * di;
        float4 xv = x[node];
        sxa[grp] = make_float4(fmaf(c0, xv.x, ax), fmaf(c0, xv.y, ay),
                               fmaf(c0, xv.z, az), fmaf(c0, xv.w, aw));
    }
    __syncthreads();

    int node0 = blockIdx.x * 16;
#pragma unroll
    for (int it = 0; it < 2; ++it) {
        int id = it * 256 + t;       // 512 units = 16 nodes x 32 col-groups
        int n = id >> 5;
        int g = id & 31;
        float4 a = sxa[n];
        float c[4];
#pragma unroll
        for (int j = 0; j < 4; ++j) {
            int col = g * 4 + j;
            float v = sb[col];
            v = fmaf(a.x, sW[col],           v);
            v = fmaf(a.y, sW[HID + col],     v);
            v = fmaf(a.z, sW[2 * HID + col], v);
            v = fmaf(a.w, sW[3 * HID + col], v);
            c[j] = fmaxf(v, 0.0f);
        }
        unsigned lo = __hip_fp8x2_e4m3(make_float2(c[0], c[1])).__x;
        unsigned hi = __hip_fp8x2_e4m3(make_float2(c[2], c[3])).__x;
        hA[(node0 + n) * 32 + g] = lo | (hi << 16);
    }
}

// ---------------- FUSED layers 2..4: Agg (fp8) -> LDS -> MFMA GEMM --------------------------
// Block = 512 thr = 8 waves = 16 nodes (2 nodes/wave), pad-8 rows, depth-2 pipeline.
template <bool FP8OUT>
__global__ __launch_bounds__(512, 8) void k_aggemm8(const unsigned* __restrict__ h8,
                                                    const int* __restrict__ rowptrP,
                                                    const unsigned* __restrict__ edges,
                                                    const float* __restrict__ dinv,
                                                    const f16* __restrict__ Wp,
                                                    const float* __restrict__ bias,
                                                    void* __restrict__ outv) {
    __shared__ f16 S[16 * HID];   // 4 KB, rows XOR-swizzled at dword granularity
    int wave = threadIdx.x >> 6;        // 0..7
    int lane = threadIdx.x & 63;
    int half = lane >> 5;               // which node of the pair
    int g    = (lane >> 4) & 1;         // group within the half
    int l    = lane & 15;
    int node0 = blockIdx.x * 16;
    int row   = wave * 2 + half;        // local row 0..15
    int node  = node0 + row;
    int beg = rowptrP[node];
    int end = rowptrP[node + 1];
    const char* hp = (const char*)h8 + l * 8;

    f16x2 acc[4];
    acc[0] = (f16x2){0, 0}; acc[1] = (f16x2){0, 0};
    acc[2] = (f16x2){0, 0}; acc[3] = (f16x2){0, 0};
    {   // self-loop term: group 0 of each half contributes; group 1 fma with coef 0
        float di = dinv[node];
        f16 c0 = (g == 0) ? (f16)(di * di) : (f16)0.f;
        f16x2 c02; c02.x = c0; c02.y = c0;
        uint2 v = *(const uint2*)(hp + ((size_t)node << 7));
        fma8h(c02, v, acc);
    }

    // depth-2 pipelined agg: 8 records/window (2 groups x dwordx4, transposed store)
    if (beg < end) {
        uint4 R = *(const uint4*)(edges + beg + g * 4);
        uint2 V0 = *(const uint2*)(hp + ((R.x >> 8) & 0xFFFFFF80u));
        uint2 V1 = *(const uint2*)(hp + ((R.y >> 8) & 0xFFFFFF80u));
        uint2 V2 = *(const uint2*)(hp + ((R.z >> 8) & 0xFFFFFF80u));
        uint2 V3 = *(const uint2*)(hp + ((R.w >> 8) & 0xFFFFFF80u));
        int e = beg;
        while (true) {
            int en = e + 8;
            bool more = en < end;
            uint4 Rc = R;
            uint2 W0 = V0, W1 = V1, W2 = V2, W3 = V3;
            if (more) R = *(const uint4*)(edges + en + g * 4);   // issue next records early
            fma8h(rec_coef2(Rc.x), W0, acc);                     // consumes PREVIOUS gathers
            fma8h(rec_coef2(Rc.y), W1, acc);
            fma8h(rec_coef2(Rc.z), W2, acc);
            fma8h(rec_coef2(Rc.w), W3, acc);
            if (!more) break;
            V0 = *(const uint2*)(hp + ((R.x >> 8) & 0xFFFFFF80u));  // issue next gathers
            V1 = *(const uint2*)(hp + ((R.y >> 8) & 0xFFFFFF80u));
            V2 = *(const uint2*)(hp + ((R.z >> 8) & 0xFFFFFF80u));
            V3 = *(const uint2*)(hp + ((R.w >> 8) & 0xFFFFFF80u));
            e = en;
        }
    }

    // combine the 2 groups of each half (xor 16 stays within each 32-lane half)
#pragma unroll
    for (int j = 0; j < 4; ++j) acc[j] += shfl_xor_h2(acc[j], 16);

    if ((lane & 16) == 0) {     // lanes 0-15 -> row 2w, lanes 32-47 -> row 2w+1
        f16x8 o;
        o[0] = acc[0][0]; o[1] = acc[0][1]; o[2] = acc[1][0]; o[3] = acc[1][1];
        o[4] = acc[2][0]; o[5] = acc[2][1]; o[6] = acc[3][0]; o[7] = acc[3][1];
        int dw = (l * 4) ^ ((row & 7) << 2);       // dword offset within row, swizzled
        *(f16x8*)&S[row * HID + dw * 2] = o;
    }
    __syncthreads();

    // GEMM phase: wave w -> col tile t = w (8 tiles, all waves busy)
    {
        int t = wave;
        int m = lane & 15;
        int q = lane >> 4;
        f32x4 c4 = (f32x4){0.f, 0.f, 0.f, 0.f};
#pragma unroll
        for (int ks = 0; ks < 4; ++ks) {
            int dw = (ks * 16 + q * 4) ^ ((m & 7) << 2);
            f16x8 a = *(const f16x8*)&S[m * HID + dw * 2];
            f16x8 b = *(const f16x8*)(Wp + ((size_t)(t * 4 + ks) * 64 + lane) * 8);
            c4 = __builtin_amdgcn_mfma_f32_16x16x32_f16(a, b, c4, 0, 0, 0);
        }
        float bb = bias[t * 16 + m];
#pragma unroll
        for (int r = 0; r < 4; ++r) {
            float val = fmaxf(c4[r] + bb, 0.0f);
            int orow = node0 + q * 4 + r;
            if constexpr (FP8OUT) {
                ((__hip_fp8_e4m3*)outv)[(size_t)orow * HID + t * 16 + m] = __hip_fp8_e4m3(val);
            } else {
                ((f16*)outv)[(size_t)orow * HID + t * 16 + m] = (f16)val;
            }
        }
    }
}

// ---------------- pack 3x W into MFMA B-fragment order + init strided bucket cursors --------
__global__ __launch_bounds__(256) void k_packW3(const float* __restrict__ W2, const float* __restrict__ W3,
                                                const float* __restrict__ W4, f16* __restrict__ Wp,
                                                int* __restrict__ gcur) {
    if (blockIdx.x == 0 && threadIdx.x < NBUK) gcur[threadIdx.x * 16] = threadIdx.x * BUKCAP;
    int idx = blockIdx.x * 256 + threadIdx.x;   // 192 blocks x 256 = 49152 = 3 * 16384
    int which = idx >> 14;
    int r = idx & 16383;
    const float* W = (which == 0) ? W2 : (which == 1) ? W3 : W4;
    int j  = r & 7;
    int L  = (r >> 3) & 63;
    int ks = (r >> 9) & 3;
    int ct = r >> 11;
    int k = ks * 32 + (L >> 4) * 8 + j;
    int n = ct * 16 + (L & 15);
    Wp[idx] = (f16)W[k * HID + n];
}

// ---------------- pooling pass 1: per (graph, segment) partial sums, fp32, deterministic -----
__device__ __forceinline__ int lower_bound_batch(const int* __restrict__ batch, int val) {
    int lo = 0, hi = N_NODES;
    while (lo < hi) { int m = (lo + hi) >> 1; if (batch[m] < val) lo = m + 1; else hi = m; }
    return lo;
}

__global__ __launch_bounds__(128) void k_pool1(const f16* __restrict__ h, const int* __restrict__ batch,
                                               float* __restrict__ partials) {
    int g = blockIdx.x / POOL_SEG;
    int s = blockIdx.x % POOL_SEG;
    int f = threadIdx.x;
    int beg = lower_bound_batch(batch, g);
    int end = lower_bound_batch(batch, g + 1);
    int len = end - beg;
    int sb = beg + (int)(((long long)len * s) / POOL_SEG);
    int se = beg + (int)(((long long)len * (s + 1)) / POOL_SEG);
    float acc = 0.0f;
    for (int i = sb; i < se; ++i) acc += (float)h[i * HID + f];
    partials[(size_t)blockIdx.x * HID + f] = acc;
}

// ---------------- pooling pass 2 + head fused ---------------
__global__ __launch_bounds__(128) void k_pool2h(const float* __restrict__ partials,
                                                const int* __restrict__ batch,
                                                const float* __restrict__ Wl, const float* __restrict__ bl,
                                                float* __restrict__ out) {
    __shared__ float sp[HID];
    int g = blockIdx.x;
    int f = threadIdx.x;
    float acc = 0.0f;
#pragma unroll
    for (int s = 0; s < POOL_SEG; ++s)
        acc += partials[(size_t)(g * POOL_SEG + s) * HID + f];
    int beg = lower_bound_batch(batch, g);
    int end = lower_bound_batch(batch, g + 1);
    sp[f] = acc / fmaxf((float)(end - beg), 1.0f);
    __syncthreads();
    if (f < N_CLS) {
        float v = bl[f];
        for (int k = 0; k < HID; ++k) v = fmaf(sp[k], Wl[k * N_CLS + f], v);
        out[g * N_CLS + f] = 1.0f / (1.0f + expf(-v));
    }
}

extern "C" void kernel_launch(void* const* d_in, const int* in_sizes, int n_in,
                              void* d_out, int out_size, void* d_ws, size_t ws_size,
                              hipStream_t stream) {
    const float* x     = (const float*)d_in[0];
    const int*   ei    = (const int*)d_in[1];
    const int*   batch = (const int*)d_in[2];
    const float* W1 = (const float*)d_in[3];  const float* b1 = (const float*)d_in[4];
    const float* W2 = (const float*)d_in[5];  const float* b2 = (const float*)d_in[6];
    const float* W3 = (const float*)d_in[7];  const float* b3 = (const float*)d_in[8];
    const float* W4 = (const float*)d_in[9];  const float* b4 = (const float*)d_in[10];
    const float* Wl = (const float*)d_in[11]; const float* bl = (const float*)d_in[12];
    float* out = (float*)d_out;

    const size_t EPAD = (size_t)N_EDGES + (size_t)N_NODES * 8 + 256;  // pad-8 capacity bound

    char* p = (char*)d_ws;
    auto alloc = [&](size_t bytes) { char* r = p; p += (bytes + 255) & ~(size_t)255; return (void*)r; };
    int*      gcur    = (int*)     alloc((size_t)NBUK * 16 * 4);      // 64B-strided cursors
    int*      padTot  = (int*)     alloc((size_t)NQB * 4);
    int*      padBase = (int*)     alloc((size_t)(NQB + 1) * 4);
    unsigned* bkt     = (unsigned*)alloc((size_t)NBUK * BUKCAP * 4);
    int*      deg     = (int*)     alloc((size_t)N_NODES * 4);
    int*      rowptrP = (int*)     alloc((size_t)(N_NODES + 1) * 4);
    float*    dinv    = (float*)   alloc((size_t)N_NODES * 4);
    unsigned* edges   = (unsigned*)alloc(EPAD * 4);
    unsigned* hA      = (unsigned*)alloc((size_t)N_NODES * HID);      // fp8 ping
    unsigned* hC      = (unsigned*)alloc((size_t)N_NODES * HID);      // fp8 pong
    f16*      h4      = (f16*)     alloc((size_t)N_NODES * HID * 2);  // fp16 final layer out
    float*    parts   = (float*)   alloc((size_t)N_GRAPH * POOL_SEG * HID * 4);
    f16*      Wp      = (f16*)     alloc((size_t)3 * HID * HID * 2);
    f16*      Wp2 = Wp;
    f16*      Wp3 = Wp + HID * HID;
    f16*      Wp4 = Wp + 2 * HID * HID;

    const int* srcv = ei;              // edge_index[0]
    const int* dstv = ei + N_EDGES;    // edge_index[1]

    // W pack + cursor init; pre-zero edges (dummy = record 0); fused count+scatter build
    k_packW3  <<<192, 256, 0, stream>>>(W2, W3, W4, Wp, gcur);
    hipMemsetAsync(edges, 0, EPAD * 4, stream);
    k_scatterA<<<NCHUNK, 256, 0, stream>>>(srcv, dstv, gcur, bkt);
    k_hist2   <<<NQB, 256, 0, stream>>>(bkt, gcur, deg, dinv, padTot);
    k_pscan   <<<1, 1024, 0, stream>>>(padTot, padBase, rowptrP);
    k_local2  <<<NQB, 256, 0, stream>>>(bkt, gcur, deg, dinv, padBase, rowptrP, edges);

    // layer 1: fused wave-parallel Agg(x) + (Nx4)@(4x128) GEMM, fp8 out
    k_aggx1<<<N_NODES / 16, 256, 0, stream>>>((const float4*)x, rowptrP, edges, dinv, W1, b1, hA);

    // layers 2..4: fused Agg (2 nodes/wave, pipelined) + MFMA GEMM, 16 nodes / 512-thr block
    const int fgrid = N_NODES / 16;   // 6250 blocks
    k_aggemm8<true ><<<fgrid, 512, 0, stream>>>(hA, rowptrP, edges, dinv, Wp2, b2, hC);
    k_aggemm8<true ><<<fgrid, 512, 0, stream>>>(hC, rowptrP, edges, dinv, Wp3, b3, hA);
    k_aggemm8<false><<<fgrid, 512, 0, stream>>>(hA, rowptrP, edges, dinv, Wp4, b4, h4);

    k_pool1 <<<N_GRAPH * POOL_SEG, 128, 0, stream>>>(h4, batch, parts);
    k_pool2h<<<N_GRAPH, 128, 0, stream>>>(parts, batch, Wl, bl, out);
}

// Round 12
// 300.495 us; speedup vs baseline: 1.0999x; 1.0999x over previous
//
#include <hip/hip_runtime.h>
#include <hip/hip_fp8.h>
#include <math.h>

#define N_NODES 100000
#define N_EDGES 1600000
#define F_IN    4
#define HID     128
#define N_CLS   5
#define N_GRAPH 256
#define POOL_SEG 8

#define BSHIFT   9
#define BSIZE    512
#define NBUK     196            // 512-node buckets: ceil(100000/512)
#define NCHUNK   200
#define CHUNK    8000           // 200 * 8000 = 1.6M exactly
#define BUKCAP   9216           // per-bucket region capacity; mean 8163, sd ~90 -> +11 sigma

typedef _Float16 f16;
typedef _Float16 f16x2 __attribute__((ext_vector_type(2)));
typedef _Float16 f16x8 __attribute__((ext_vector_type(8)));
typedef float f32x4 __attribute__((ext_vector_type(4)));

// decode 4-byte edge record: [src:17 | coef-f16-positive:15]; record 0 == dummy (src 0, coef 0)
__device__ __forceinline__ float rec_coef(unsigned r) {
    return (float)__builtin_bit_cast(_Float16, (unsigned short)(r & 0x7FFFu));
}

// coef broadcast into both halves of a f16x2
__device__ __forceinline__ f16x2 rec_coef2(unsigned r) {
    unsigned c = r & 0x7FFFu;
    return __builtin_bit_cast(f16x2, (c << 16) | c);
}

__device__ __forceinline__ float2 fp8x2_to_f32x2(unsigned short raw) {
    __hip_fp8x2_e4m3 t;
    t.__x = raw;
    return static_cast<float2>(t);
}

// 2 fp8 bytes -> f16x2. gfx950 has V_CVT_PK_F16_FP8 (1 VALU); fallback via f32.
#if __has_builtin(__builtin_amdgcn_cvt_pk_f16_fp8)
__device__ __forceinline__ f16x2 cvt_h2(unsigned v) {
    auto t = __builtin_amdgcn_cvt_pk_f16_fp8((short)v);
    return __builtin_bit_cast(f16x2, t);
}
#else
__device__ __forceinline__ f16x2 cvt_h2(unsigned v) {
    float2 f = fp8x2_to_f32x2((unsigned short)v);
    auto t = __builtin_amdgcn_cvt_pkrtz(f.x, f.y);
    return __builtin_bit_cast(f16x2, t);
}
#endif

// 8 fp8 values (uint2) -> packed-f16 fma into acc[0..3] with coef pair c2 (v_pk_fma_f16)
__device__ __forceinline__ void fma8h(f16x2 c2, uint2 v, f16x2* acc) {
    acc[0] += c2 * cvt_h2(v.x);
    acc[1] += c2 * cvt_h2(v.x >> 16);
    acc[2] += c2 * cvt_h2(v.y);
    acc[3] += c2 * cvt_h2(v.y >> 16);
}

__device__ __forceinline__ f16x2 shfl_xor_h2(f16x2 a, int m) {
    return __builtin_bit_cast(f16x2, __shfl_xor(__builtin_bit_cast(int, a), m, 64));
}

// ================= CSR BUILD =================================================================
// Lessons: (r7) scattered 4B global writes cost a 64B line each -> scatters stay bucket-local
// and cursor-sequential; (r8) per-edge random global atomics are line-amplified and
// latency-bound -> degree via LDS histograms only; (r10) bucket bases via atomic range
// reservation (one atomic per block-bucket); (r11) quarter-bucket splitting and 800-block
// scatter REGRESSED (read-amp + partial-line writes) -> back to r10 geometry; (r12) the
// scatter is latency-bound at 0.8 blocks/CU -> int4-vectorize its edge-list loads.

// fused count+scatter: per chunk-block, (1) LDS histogram, (2) reserve [base,base+cnt) per
// bucket via global cursor, (3) re-scan chunk (L2-hot) and scatter through LDS cursors.
// record: (src:17)<<9 | (dst & 511). Within-bucket order is arbitrary (consumers don't care).
__global__ __launch_bounds__(256) void k_scatterA(const int4* __restrict__ src4, const int4* __restrict__ dst4,
                                                  int* __restrict__ gcur, unsigned* __restrict__ bkt) {
    __shared__ int cnt[NBUK];
    __shared__ int cur[NBUK];
    int t = threadIdx.x;
    if (t < NBUK) cnt[t] = 0;
    __syncthreads();
    int base4 = blockIdx.x * (CHUNK / 4);           // 2000 int4 per chunk
#pragma unroll
    for (int it = 0; it < 8; ++it) {
        int i4 = it * 256 + t;
        if (i4 < CHUNK / 4) {
            int4 d = dst4[base4 + i4];
            atomicAdd(&cnt[d.x >> BSHIFT], 1);
            atomicAdd(&cnt[d.y >> BSHIFT], 1);
            atomicAdd(&cnt[d.z >> BSHIFT], 1);
            atomicAdd(&cnt[d.w >> BSHIFT], 1);
        }
    }
    __syncthreads();
    if (t < NBUK) cur[t] = atomicAdd(&gcur[t], cnt[t]);   // reserve contiguous range
    __syncthreads();
#pragma unroll
    for (int it = 0; it < 8; ++it) {
        int i4 = it * 256 + t;
        if (i4 < CHUNK / 4) {
            int4 d = dst4[base4 + i4];
            int4 s = src4[base4 + i4];
            int p0 = atomicAdd(&cur[d.x >> BSHIFT], 1);
            bkt[p0] = ((unsigned)s.x << BSHIFT) | (unsigned)(d.x & (BSIZE - 1));
            int p1 = atomicAdd(&cur[d.y >> BSHIFT], 1);
            bkt[p1] = ((unsigned)s.y << BSHIFT) | (unsigned)(d.y & (BSIZE - 1));
            int p2 = atomicAdd(&cur[d.z >> BSHIFT], 1);
            bkt[p2] = ((unsigned)s.z << BSHIFT) | (unsigned)(d.z & (BSIZE - 1));
            int p3 = atomicAdd(&cur[d.w >> BSHIFT], 1);
            bkt[p3] = ((unsigned)s.w << BSHIFT) | (unsigned)(d.w & (BSIZE - 1));
        }
    }
}

// per-bucket degree hist (LDS-local, from bkt) -> deg, dinv, pad-8 bucket total.
// bucket b's records live in [b*BUKCAP, gcur[b]).
__global__ __launch_bounds__(256) void k_hist2(const unsigned* __restrict__ bkt,
                                               const int* __restrict__ gcur,
                                               int* __restrict__ deg, float* __restrict__ dinv,
                                               int* __restrict__ padTot) {
    __shared__ int hist[BSIZE];
    __shared__ int tot;
    int t = threadIdx.x, b = blockIdx.x;
    hist[t] = 0; hist[t + 256] = 0;
    if (t == 0) tot = 0;
    __syncthreads();
    int s0 = b * BUKCAP, s1 = gcur[b];
    for (int e = s0 + t; e < s1; e += 256) atomicAdd(&hist[bkt[e] & (BSIZE - 1)], 1);
    __syncthreads();
    int loc = 0;
#pragma unroll
    for (int h = 0; h < 2; ++h) {
        int l = t + h * 256;
        int node = b * BSIZE + l;
        int d = hist[l];
        if (node < N_NODES) {
            deg[node] = d;
            dinv[node] = rsqrtf((float)d + 1.0f);
        }
        loc += (d + 7) >> 3;
    }
    atomicAdd(&tot, loc);
    __syncthreads();
    if (t == 0) padTot[b] = tot << 3;
}

// scan padded bucket totals -> padded bases.
__global__ __launch_bounds__(256) void k_pscan(const int* __restrict__ padTot, int* __restrict__ padBase,
                                               int* __restrict__ rowptrP) {
    __shared__ int s[256];
    int b = threadIdx.x;
    int v = (b < NBUK) ? padTot[b] : 0;
    s[b] = v;
    __syncthreads();
    for (int off = 1; off < 256; off <<= 1) {
        int u = (b >= off) ? s[b - off] : 0;
        __syncthreads();
        s[b] += u;
        __syncthreads();
    }
    if (b < NBUK) padBase[b] = s[b] - v;
    if (b == 0) {
        padBase[NBUK] = s[NBUK - 1];
        rowptrP[N_NODES] = s[NBUK - 1];
    }
}

// per-bucket padded CSR (pad-8) + coef fused; dummy slots = record 0.
// Records stored 2x4-TRANSPOSED within each 8-slot window: logical slot 2i+g lands at
// physical 4g+i; one dwordx4 at (win + g*4) gives group g its 4 records directly.
// All writes land in this bucket's ~L2-resident padded region (densely overwritten).
__global__ __launch_bounds__(256) void k_local2(const unsigned* __restrict__ bkt,
                                                const int* __restrict__ gcur,
                                                const int* __restrict__ deg,
                                                const float* __restrict__ dinv,
                                                const int* __restrict__ padBase,
                                                int* __restrict__ rowptrP,
                                                unsigned* __restrict__ edges) {
    __shared__ int sc[BSIZE];
    __shared__ int cur[BSIZE];
    __shared__ int st[BSIZE];
    __shared__ float dv[BSIZE];
    int t = threadIdx.x, b = blockIdx.x;
    int base = padBase[b];
    int n0 = b * BSIZE + t, n1 = n0 + 256;
    int d0 = (n0 < N_NODES) ? deg[n0] : 0;
    int d1 = (n1 < N_NODES) ? deg[n1] : 0;
    int p0 = ((d0 + 7) >> 3) << 3;
    int p1 = ((d1 + 7) >> 3) << 3;
    sc[t] = p0; sc[t + 256] = p1;
    dv[t] = (n0 < N_NODES) ? dinv[n0] : 0.f;
    dv[t + 256] = (n1 < N_NODES) ? dinv[n1] : 0.f;
    __syncthreads();
    for (int off = 1; off < BSIZE; off <<= 1) {
        int i0 = t, i1 = t + 256;
        int v0 = (i0 >= off) ? sc[i0 - off] : 0;
        int v1 = (i1 >= off) ? sc[i1 - off] : 0;
        __syncthreads();
        sc[i0] += v0; sc[i1] += v1;
        __syncthreads();
    }
    int off0 = base + sc[t] - p0;
    int off1 = base + sc[t + 256] - p1;
    if (n0 < N_NODES) rowptrP[n0] = off0;
    if (n1 < N_NODES) rowptrP[n1] = off1;
    cur[t] = off0; cur[t + 256] = off1;
    st[t]  = off0; st[t + 256]  = off1;
    int padT = sc[BSIZE - 1];
    // init padded region to dummy (record 0 = src 0, coef 0)
    for (int i = base + t; i < base + padT; i += 256) edges[i] = 0;
    __syncthreads();
    int s0 = b * BUKCAP, s1 = gcur[b];
    for (int e = s0 + t; e < s1; e += 256) {
        unsigned r = bkt[e];
        int dl = (int)(r & (BSIZE - 1));
        int s = (int)(r >> BSHIFT);
        int p = atomicAdd(&cur[dl], 1);
        int rs = st[dl];
        int sl = p - rs;                                   // logical slot in row
        int phys = rs + (sl & ~7) + (((sl & 1) << 2) | ((sl >> 1) & 3)); // 2x4 transpose in window-8
        float c = dv[dl] * dinv[s];
        unsigned short cb = __builtin_bit_cast(unsigned short, (f16)c);
        edges[phys] = ((unsigned)s << 15) | (unsigned)(cb & 0x7FFFu);
    }
}

// ---------------- FUSED layer 1: wave-parallel Agg(x) + (Nx4)@(4x128) GEMM, fp8 out ---------
// Block = 256 thr = 16 node-groups of 16 lanes. Length-guarded loop -> pad-8 safe; the
// window transpose only permutes the order of an order-insensitive lane-sum.
__global__ __launch_bounds__(256) void k_aggx1(const float4* __restrict__ x,
                                               const int* __restrict__ rowptrP,
                                               const unsigned* __restrict__ edges,
                                               const float* __restrict__ dinv,
                                               const float* __restrict__ W1, const float* __restrict__ b1,
                                               unsigned* __restrict__ hA) {
    __shared__ float4 sxa[16];
    __shared__ float sW[4 * HID];
    __shared__ float sb[HID];
    int t = threadIdx.x;
    sW[t] = W1[t];
    sW[t + 256] = W1[t + 256];
    if (t < HID) sb[t] = b1[t];
    int grp = t >> 4;             // 0..15 local node
    int l = t & 15;
    int node = blockIdx.x * 16 + grp;   // grid 6250 -> exact
    int beg = rowptrP[node], end = rowptrP[node + 1];
    float ax = 0.f, ay = 0.f, az = 0.f, aw = 0.f;
    for (int e = beg + l; e < end; e += 16) {
        unsigned r = edges[e];
        float c = rec_coef(r);
        float4 v = x[r >> 15];
        ax = fmaf(c, v.x, ax); ay = fmaf(c, v.y, ay);
        az = fmaf(c, v.z, az); aw = fmaf(c, v.w, aw);
    }
#pragma unroll
    for (int off = 1; off < 16; off <<= 1) {
        ax += __shfl_xor(ax, off, 64);
        ay += __shfl_xor(ay, off, 64);
        az += __shfl_xor(az, off, 64);
        aw += __shfl_xor(aw, off, 64);
    }
    if (l == 0) {
        float di = dinv[node];
        float c0 = di * di;
        float4 xv = x[node];
        sxa[grp] = make_float4(fmaf(c0, xv.x, ax), fmaf(c0, xv.y, ay),
                               fmaf(c0, xv.z, az), fmaf(c0, xv.w, aw));
    }
    __syncthreads();

    int node0 = blockIdx.x * 16;
#pragma unroll
    for (int it = 0; it < 2; ++it) {
        int id = it * 256 + t;       // 512 units = 16 nodes x 32 col-groups
        int n = id >> 5;
        int g = id & 31;
        float4 a = sxa[n];
        float c[4];
#pragma unroll
        for (int j = 0; j < 4; ++j) {
            int col = g * 4 + j;
            float v = sb[col];
            v = fmaf(a.x, sW[col],           v);
            v = fmaf(a.y, sW[HID + col],     v);
            v = fmaf(a.z, sW[2 * HID + col], v);
            v = fmaf(a.w, sW[3 * HID + col], v);
            c[j] = fmaxf(v, 0.0f);
        }
        unsigned lo = __hip_fp8x2_e4m3(make_float2(c[0], c[1])).__x;
        unsigned hi = __hip_fp8x2_e4m3(make_float2(c[2], c[3])).__x;
        hA[(node0 + n) * 32 + g] = lo | (hi << 16);
    }
}

// ---------------- FUSED layers 2..4: Agg (fp8) -> LDS -> MFMA GEMM --------------------------
// Block = 512 thr = 8 waves = 16 nodes (2 nodes/wave), pad-8 rows, depth-2 pipeline.
template <bool FP8OUT>
__global__ __launch_bounds__(512, 8) void k_aggemm8(const unsigned* __restrict__ h8,
                                                    const int* __restrict__ rowptrP,
                                                    const unsigned* __restrict__ edges,
                                                    const float* __restrict__ dinv,
                                                    const f16* __restrict__ Wp,
                                                    const float* __restrict__ bias,
                                                    void* __restrict__ outv) {
    __shared__ f16 S[16 * HID];   // 4 KB, rows XOR-swizzled at dword granularity
    int wave = threadIdx.x >> 6;        // 0..7
    int lane = threadIdx.x & 63;
    int half = lane >> 5;               // which node of the pair
    int g    = (lane >> 4) & 1;         // group within the half
    int l    = lane & 15;
    int node0 = blockIdx.x * 16;
    int row   = wave * 2 + half;        // local row 0..15
    int node  = node0 + row;
    int beg = rowptrP[node];
    int end = rowptrP[node + 1];
    const char* hp = (const char*)h8 + l * 8;

    f16x2 acc[4];
    acc[0] = (f16x2){0, 0}; acc[1] = (f16x2){0, 0};
    acc[2] = (f16x2){0, 0}; acc[3] = (f16x2){0, 0};
    {   // self-loop term: group 0 of each half contributes; group 1 fma with coef 0
        float di = dinv[node];
        f16 c0 = (g == 0) ? (f16)(di * di) : (f16)0.f;
        f16x2 c02; c02.x = c0; c02.y = c0;
        uint2 v = *(const uint2*)(hp + ((size_t)node << 7));
        fma8h(c02, v, acc);
    }

    // depth-2 pipelined agg: 8 records/window (2 groups x dwordx4, transposed store)
    if (beg < end) {
        uint4 R = *(const uint4*)(edges + beg + g * 4);
        uint2 V0 = *(const uint2*)(hp + ((R.x >> 8) & 0xFFFFFF80u));
        uint2 V1 = *(const uint2*)(hp + ((R.y >> 8) & 0xFFFFFF80u));
        uint2 V2 = *(const uint2*)(hp + ((R.z >> 8) & 0xFFFFFF80u));
        uint2 V3 = *(const uint2*)(hp + ((R.w >> 8) & 0xFFFFFF80u));
        int e = beg;
        while (true) {
            int en = e + 8;
            bool more = en < end;
            uint4 Rc = R;
            uint2 W0 = V0, W1 = V1, W2 = V2, W3 = V3;
            if (more) R = *(const uint4*)(edges + en + g * 4);   // issue next records early
            fma8h(rec_coef2(Rc.x), W0, acc);                     // consumes PREVIOUS gathers
            fma8h(rec_coef2(Rc.y), W1, acc);
            fma8h(rec_coef2(Rc.z), W2, acc);
            fma8h(rec_coef2(Rc.w), W3, acc);
            if (!more) break;
            V0 = *(const uint2*)(hp + ((R.x >> 8) & 0xFFFFFF80u));  // issue next gathers
            V1 = *(const uint2*)(hp + ((R.y >> 8) & 0xFFFFFF80u));
            V2 = *(const uint2*)(hp + ((R.z >> 8) & 0xFFFFFF80u));
            V3 = *(const uint2*)(hp + ((R.w >> 8) & 0xFFFFFF80u));
            e = en;
        }
    }

    // combine the 2 groups of each half (xor 16 stays within each 32-lane half)
#pragma unroll
    for (int j = 0; j < 4; ++j) acc[j] += shfl_xor_h2(acc[j], 16);

    if ((lane & 16) == 0) {     // lanes 0-15 -> row 2w, lanes 32-47 -> row 2w+1
        f16x8 o;
        o[0] = acc[0][0]; o[1] = acc[0][1]; o[2] = acc[1][0]; o[3] = acc[1][1];
        o[4] = acc[2][0]; o[5] = acc[2][1]; o[6] = acc[3][0]; o[7] = acc[3][1];
        int dw = (l * 4) ^ ((row & 7) << 2);       // dword offset within row, swizzled
        *(f16x8*)&S[row * HID + dw * 2] = o;
    }
    __syncthreads();

    // GEMM phase: wave w -> col tile t = w (8 tiles, all waves busy)
    {
        int t = wave;
        int m = lane & 15;
        int q = lane >> 4;
        f32x4 c4 = (f32x4){0.f, 0.f, 0.f, 0.f};
#pragma unroll
        for (int ks = 0; ks < 4; ++ks) {
            int dw = (ks * 16 + q * 4) ^ ((m & 7) << 2);
            f16x8 a = *(const f16x8*)&S[m * HID + dw * 2];
            f16x8 b = *(const f16x8*)(Wp + ((size_t)(t * 4 + ks) * 64 + lane) * 8);
            c4 = __builtin_amdgcn_mfma_f32_16x16x32_f16(a, b, c4, 0, 0, 0);
        }
        float bb = bias[t * 16 + m];
#pragma unroll
        for (int r = 0; r < 4; ++r) {
            float val = fmaxf(c4[r] + bb, 0.0f);
            int orow = node0 + q * 4 + r;
            if constexpr (FP8OUT) {
                ((__hip_fp8_e4m3*)outv)[(size_t)orow * HID + t * 16 + m] = __hip_fp8_e4m3(val);
            } else {
                ((f16*)outv)[(size_t)orow * HID + t * 16 + m] = (f16)val;
            }
        }
    }
}

// ---------------- pack 3x W into MFMA B-fragment order + init bucket cursors ----------------
__global__ __launch_bounds__(256) void k_packW3(const float* __restrict__ W2, const float* __restrict__ W3,
                                                const float* __restrict__ W4, f16* __restrict__ Wp,
                                                int* __restrict__ gcur) {
    if (blockIdx.x == 0 && threadIdx.x < NBUK) gcur[threadIdx.x] = threadIdx.x * BUKCAP;
    int idx = blockIdx.x * 256 + threadIdx.x;   // 192 blocks x 256 = 49152 = 3 * 16384
    int which = idx >> 14;
    int r = idx & 16383;
    const float* W = (which == 0) ? W2 : (which == 1) ? W3 : W4;
    int j  = r & 7;
    int L  = (r >> 3) & 63;
    int ks = (r >> 9) & 3;
    int ct = r >> 11;
    int k = ks * 32 + (L >> 4) * 8 + j;
    int n = ct * 16 + (L & 15);
    Wp[idx] = (f16)W[k * HID + n];
}

// ---------------- pooling pass 1: per (graph, segment) partial sums, fp32, deterministic -----
__device__ __forceinline__ int lower_bound_batch(const int* __restrict__ batch, int val) {
    int lo = 0, hi = N_NODES;
    while (lo < hi) { int m = (lo + hi) >> 1; if (batch[m] < val) lo = m + 1; else hi = m; }
    return lo;
}

__global__ __launch_bounds__(128) void k_pool1(const f16* __restrict__ h, const int* __restrict__ batch,
                                               float* __restrict__ partials) {
    int g = blockIdx.x / POOL_SEG;
    int s = blockIdx.x % POOL_SEG;
    int f = threadIdx.x;
    int beg = lower_bound_batch(batch, g);
    int end = lower_bound_batch(batch, g + 1);
    int len = end - beg;
    int sb = beg + (int)(((long long)len * s) / POOL_SEG);
    int se = beg + (int)(((long long)len * (s + 1)) / POOL_SEG);
    float acc = 0.0f;
    for (int i = sb; i < se; ++i) acc += (float)h[i * HID + f];
    partials[(size_t)blockIdx.x * HID + f] = acc;
}

// ---------------- pooling pass 2 + head fused ---------------
__global__ __launch_bounds__(128) void k_pool2h(const float* __restrict__ partials,
                                                const int* __restrict__ batch,
                                                const float* __restrict__ Wl, const float* __restrict__ bl,
                                                float* __restrict__ out) {
    __shared__ float sp[HID];
    int g = blockIdx.x;
    int f = threadIdx.x;
    float acc = 0.0f;
#pragma unroll
    for (int s = 0; s < POOL_SEG; ++s)
        acc += partials[(size_t)(g * POOL_SEG + s) * HID + f];
    int beg = lower_bound_batch(batch, g);
    int end = lower_bound_batch(batch, g + 1);
    sp[f] = acc / fmaxf((float)(end - beg), 1.0f);
    __syncthreads();
    if (f < N_CLS) {
        float v = bl[f];
        for (int k = 0; k < HID; ++k) v = fmaf(sp[k], Wl[k * N_CLS + f], v);
        out[g * N_CLS + f] = 1.0f / (1.0f + expf(-v));
    }
}

extern "C" void kernel_launch(void* const* d_in, const int* in_sizes, int n_in,
                              void* d_out, int out_size, void* d_ws, size_t ws_size,
                              hipStream_t stream) {
    const float* x     = (const float*)d_in[0];
    const int*   ei    = (const int*)d_in[1];
    const int*   batch = (const int*)d_in[2];
    const float* W1 = (const float*)d_in[3];  const float* b1 = (const float*)d_in[4];
    const float* W2 = (const float*)d_in[5];  const float* b2 = (const float*)d_in[6];
    const float* W3 = (const float*)d_in[7];  const float* b3 = (const float*)d_in[8];
    const float* W4 = (const float*)d_in[9];  const float* b4 = (const float*)d_in[10];
    const float* Wl = (const float*)d_in[11]; const float* bl = (const float*)d_in[12];
    float* out = (float*)d_out;

    const size_t EPAD = (size_t)N_EDGES + (size_t)N_NODES * 8 + 256;  // pad-8 capacity bound

    char* p = (char*)d_ws;
    auto alloc = [&](size_t bytes) { char* r = p; p += (bytes + 255) & ~(size_t)255; return (void*)r; };
    int*      gcur    = (int*)     alloc((size_t)NBUK * 4);
    int*      padTot  = (int*)     alloc((size_t)NBUK * 4);
    int*      padBase = (int*)     alloc((size_t)(NBUK + 1) * 4);
    unsigned* bkt     = (unsigned*)alloc((size_t)NBUK * BUKCAP * 4);
    int*      deg     = (int*)     alloc((size_t)N_NODES * 4);
    int*      rowptrP = (int*)     alloc((size_t)(N_NODES + 1) * 4);
    float*    dinv    = (float*)   alloc((size_t)N_NODES * 4);
    unsigned* edges   = (unsigned*)alloc(EPAD * 4);
    unsigned* hA      = (unsigned*)alloc((size_t)N_NODES * HID);      // fp8 ping
    unsigned* hC      = (unsigned*)alloc((size_t)N_NODES * HID);      // fp8 pong
    f16*      h4      = (f16*)     alloc((size_t)N_NODES * HID * 2);  // fp16 final layer out
    float*    parts   = (float*)   alloc((size_t)N_GRAPH * POOL_SEG * HID * 4);
    f16*      Wp      = (f16*)     alloc((size_t)3 * HID * HID * 2);
    f16*      Wp2 = Wp;
    f16*      Wp3 = Wp + HID * HID;
    f16*      Wp4 = Wp + 2 * HID * HID;

    const int* srcv = ei;              // edge_index[0]
    const int* dstv = ei + N_EDGES;    // edge_index[1]

    // W pack + bucket-cursor init (same launch), then fused count+scatter CSR build
    k_packW3  <<<192, 256, 0, stream>>>(W2, W3, W4, Wp, gcur);
    k_scatterA<<<NCHUNK, 256, 0, stream>>>((const int4*)srcv, (const int4*)dstv, gcur, bkt);
    k_hist2   <<<NBUK, 256, 0, stream>>>(bkt, gcur, deg, dinv, padTot);
    k_pscan   <<<1, 256, 0, stream>>>(padTot, padBase, rowptrP);
    k_local2  <<<NBUK, 256, 0, stream>>>(bkt, gcur, deg, dinv, padBase, rowptrP, edges);

    // layer 1: fused wave-parallel Agg(x) + (Nx4)@(4x128) GEMM, fp8 out
    k_aggx1<<<N_NODES / 16, 256, 0, stream>>>((const float4*)x, rowptrP, edges, dinv, W1, b1, hA);

    // layers 2..4: fused Agg (2 nodes/wave, pipelined) + MFMA GEMM, 16 nodes / 512-thr block
    const int fgrid = N_NODES / 16;   // 6250 blocks
    k_aggemm8<true ><<<fgrid, 512, 0, stream>>>(hA, rowptrP, edges, dinv, Wp2, b2, hC);
    k_aggemm8<true ><<<fgrid, 512, 0, stream>>>(hC, rowptrP, edges, dinv, Wp3, b3, hA);
    k_aggemm8<false><<<fgrid, 512, 0, stream>>>(hA, rowptrP, edges, dinv, Wp4, b4, h4);

    k_pool1 <<<N_GRAPH * POOL_SEG, 128, 0, stream>>>(h4, batch, parts);
    k_pool2h<<<N_GRAPH, 128, 0, stream>>>(parts, batch, Wl, bl, out);
}